// Round 1
// baseline (127.291 us; speedup 1.0000x reference)
//
#include <hip/hip_runtime.h>
#include <stdint.h>
#include <limits.h>

// Problem constants (match reference)
constexpr int BB      = 4;
constexpr int NN      = 8192;
constexpr int NPOINT  = 2048;
constexpr int CC      = 64;
constexpr int NSAMPLE = 32;
constexpr int KTOT    = NSAMPLE + 1;   // fps_idx prepended -> 33
constexpr int NCH     = 3 + 3 + CC;    // 70 output channels
constexpr int CHS     = NPOINT * KTOT; // channel stride in out = 67584

// Spatial grid: 5x5x5 cells of 0.2 over [0,1]^3.
constexpr int   GG     = 5;
constexpr int   NCELL  = GG * GG * GG;        // 125
constexpr float RPADF  = 0.1001f;             // conservative cell-range radius
constexpr int   CAND_CAP = 192;               // in-ball ~Poisson(34); +27 sigma

__device__ __forceinline__ int cell_of(float x, float y, float z) {
    int ix = (int)floorf(x * 5.0f); ix = ix < 0 ? 0 : (ix > 4 ? 4 : ix);
    int iy = (int)floorf(y * 5.0f); iy = iy < 0 ? 0 : (iy > 4 ? 4 : iy);
    int iz = (int)floorf(z * 5.0f); iz = iz < 0 ? 0 : (iz > 4 ? 4 : iz);
    return (ix * GG + iy) * GG + iz;
}

// ---------------------------------------------------------------------------
// Kernel A: fused grid build. One 1024-thread block per batch: LDS histogram,
// wave-0 scan, LDS-cursor scatter into cell-sorted AoS float4
// (x,y,z,bitcast(origidx)). Points cached in registers between phases.
// ---------------------------------------------------------------------------
__global__ __launch_bounds__(1024) void grid_build(
    const float* __restrict__ xyz, int* __restrict__ cellstartg,
    float4* __restrict__ spt)
{
    __shared__ int hist[NCELL];
    __shared__ int csl[NCELL + 1];
    __shared__ int cur[NCELL];
    const int b = blockIdx.x;
    const int t = threadIdx.x;
    if (t < NCELL) hist[t] = 0;
    __syncthreads();
    const float* xb = xyz + (size_t)b * NN * 3;
    float px[NN / 1024], py[NN / 1024], pz[NN / 1024];
    int   pc[NN / 1024];
#pragma unroll
    for (int k = 0; k < NN / 1024; ++k) {
        const float* p = xb + (size_t)(t + k * 1024) * 3;
        px[k] = p[0]; py[k] = p[1]; pz[k] = p[2];
        pc[k] = cell_of(px[k], py[k], pz[k]);
        atomicAdd(&hist[pc[k]], 1);
    }
    __syncthreads();
    if (t < 64) {                         // wave 0: scan 125 counts
        int x0 = hist[t];
        int x1 = (t + 64 < NCELL) ? hist[t + 64] : 0;
#pragma unroll
        for (int d = 1; d < 64; d <<= 1) {
            int t0 = __shfl_up(x0, d);
            int t1 = __shfl_up(x1, d);
            if (t >= d) { x0 += t0; x1 += t1; }
        }
        x1 += __shfl(x0, 63);
        if (t == 0) csl[0] = 0;
        csl[1 + t] = x0;
        if (t <= 60) csl[65 + t] = x1;
    }
    __syncthreads();
    if (t < NCELL + 1) cellstartg[b * (NCELL + 1) + t] = csl[t];
    if (t < NCELL)     cur[t] = csl[t];
    __syncthreads();
#pragma unroll
    for (int k = 0; k < NN / 1024; ++k) {
        const int pos = atomicAdd(&cur[pc[k]], 1);
        spt[b * NN + pos] = make_float4(px[k], py[k], pz[k],
                                        __int_as_float(t + k * 1024));
    }
}

// ---------------------------------------------------------------------------
// Kernel C: features (B,C,N) -> ft (B,N,C), LDS-tiled 64x64. (unchanged)
// ---------------------------------------------------------------------------
__global__ __launch_bounds__(256) void feat_transpose(
    const float* __restrict__ f, float* __restrict__ ft)
{
    __shared__ float tile[64 * 65];
    const int blk = blockIdx.x;          // B * (N/64) = 512
    const int b   = blk >> 7;
    const int n0  = (blk & 127) << 6;
    const int w   = threadIdx.x >> 6, l = threadIdx.x & 63;
#pragma unroll
    for (int i = 0; i < 16; ++i) {
        const int c = i * 4 + w;
        tile[l * 65 + c] = f[((size_t)b * CC + c) * NN + n0 + l];  // coalesced read
    }
    __syncthreads();
#pragma unroll
    for (int i = 0; i < 16; ++i) {
        const int flat = i * 256 + threadIdx.x;                    // n*64 + c
        ft[((size_t)b * NN + n0) * CC + flat] = tile[(flat >> 6) * 65 + (flat & 63)];
    }
}

// ---------------------------------------------------------------------------
// Kernel BG (NEW, fuses old kernels B+D): ball query + gather in one kernel.
// Block = 256 threads = 4 waves = 4 consecutive centroids (same batch since
// NPOINT % 4 == 0). Phase 1: each wave runs the grid ball query (identical
// arithmetic to the verified ball_query_grid) and writes its 33 ids to LDS
// sid[w][] instead of a global idx buffer — removes the ~9 MB idx HBM
// round-trip and one kernel launch, and lets the latency-bound query phase
// pipeline against other blocks' store streams.
// Phase 2: the block's 4*33 = 132 output slots are CONTIGUOUS in the
// (b, ch, j*KTOT+s) layout, so threads 0..131 each own one slot: load the
// 256B feature row as 16 independent float4s, store all 70 channels directly.
// Per channel, a wave's active lanes store 64 consecutive floats (256B,
// fully coalesced) — no LDS tile needed (only 3.6 KB LDS -> high occupancy).
// ---------------------------------------------------------------------------
__global__ __launch_bounds__(256) void bq_gather_fused(
    const float4* __restrict__ spt, const int* __restrict__ cellstart,
    const float* __restrict__ xyz, const float* __restrict__ new_xyz,
    const float4* __restrict__ ft4, const int* __restrict__ fps_idx,
    float* __restrict__ out)
{
    __shared__ int cand[4][CAND_CAP];
    __shared__ int sid[4][KTOT];

    const int w    = threadIdx.x >> 6;
    const int lane = threadIdx.x & 63;
    const int wave = blockIdx.x * 4 + w;     // centroid id, 0..8191
    const int b    = wave >> 11;             // / NPOINT

    // ---- Phase 1: grid ball query (same math as verified ball_query_grid) --
    {
        const float* cp = new_xyz + (size_t)wave * 3;
        const float cx = cp[0], cy = cp[1], cz = cp[2];
        const float r2 = __fmul_rn(0.1f, 0.1f);

        int ix0 = (int)floorf((cx - RPADF) * 5.0f); ix0 = ix0 < 0 ? 0 : ix0;
        int ix1 = (int)floorf((cx + RPADF) * 5.0f); ix1 = ix1 > 4 ? 4 : ix1;
        int iy0 = (int)floorf((cy - RPADF) * 5.0f); iy0 = iy0 < 0 ? 0 : iy0;
        int iy1 = (int)floorf((cy + RPADF) * 5.0f); iy1 = iy1 > 4 ? 4 : iy1;
        int iz0 = (int)floorf((cz - RPADF) * 5.0f); iz0 = iz0 < 0 ? 0 : iz0;
        int iz1 = (int)floorf((cz + RPADF) * 5.0f); iz1 = iz1 > 4 ? 4 : iz1;

        const int* cs = cellstart + b * (NCELL + 1);
        const int gb  = b * NN;
        int cnt = 0;

        for (int ix = ix0; ix <= ix1; ++ix) {
            for (int iy = iy0; iy <= iy1; ++iy) {
                const int cbase = (ix * GG + iy) * GG;
                const int st = cs[cbase + iz0];
                const int en = cs[cbase + iz1 + 1];
                for (int base = st; base < en; base += 64) {
                    const int pos = base + lane;
                    const bool inb = pos < en;
                    const float4 q = spt[gb + (inb ? pos : st)];
                    const int oid = __float_as_int(q.w);
                    const float dx = __fsub_rn(cx, q.x);
                    const float dy = __fsub_rn(cy, q.y);
                    const float dz = __fsub_rn(cz, q.z);
                    const float d2 = __fadd_rn(__fadd_rn(__fmul_rn(dx, dx), __fmul_rn(dy, dy)),
                                               __fmul_rn(dz, dz));
                    const bool valid = inb && (d2 < r2);
                    const unsigned long long m = __ballot(valid);
                    if (m != 0ull) {
                        const int prefix = __builtin_amdgcn_mbcnt_hi(
                            (unsigned)(m >> 32), __builtin_amdgcn_mbcnt_lo((unsigned)m, 0u));
                        const int slot = cnt + prefix;
                        if (valid && slot < CAND_CAP) cand[w][slot] = oid;
                        cnt += (int)__popcll(m);
                    }
                }
            }
        }

        const int K = cnt > CAND_CAP ? CAND_CAP : cnt;

        int v0 = (lane       < K) ? cand[w][lane]       : INT_MAX;
        int v1 = (lane + 64  < K) ? cand[w][lane + 64]  : INT_MAX;
        int v2 = (lane + 128 < K) ? cand[w][lane + 128] : INT_MAX;
        int rk0 = 0, rk1 = 0, rk2 = 0;
        for (int j = 0; j < K; ++j) {
            const int sv = cand[w][j];
            rk0 += (sv < v0); rk1 += (sv < v1); rk2 += (sv < v2);
        }
        if (lane       < K && rk0 < NSAMPLE) sid[w][1 + rk0] = v0;
        if (lane + 64  < K && rk1 < NSAMPLE) sid[w][1 + rk1] = v1;
        if (lane + 128 < K && rk2 < NSAMPLE) sid[w][1 + rk2] = v2;

        if (K < NSAMPLE) {
            int mn = v0;
#pragma unroll
            for (int off = 32; off >= 1; off >>= 1) {
                const int o = __shfl_xor(mn, off);
                mn = o < mn ? o : mn;
            }
            const int pad = (K > 0) ? mn : 0;
            if (lane >= K && lane < NSAMPLE) sid[w][1 + lane] = pad;
        }
        if (lane == 0) sid[w][0] = fps_idx[wave];
    }

    __syncthreads();

    // ---- Phase 2: gather. Thread t (< 132) owns output slot col = t of the
    // block's contiguous 132-slot range. ------------------------------------
    const int t = threadIdx.x;
    if (t < 4 * KTOT) {
        const int w2 = t / KTOT;                 // centroid-in-block (magic div)
        const int s  = t - w2 * KTOT;            // slot within centroid
        const int c0 = blockIdx.x * 4;           // first centroid (global)
        const int j  = c0 + w2;                  // global centroid id
        const int bb = c0 >> 11;                 // batch (same for all 4)
        const int id = sid[w2][s];

        // Issue the 16 independent feature-row loads first (256B contiguous).
        const float4* row = ft4 + ((size_t)bb * NN + id) * (CC / 4);
        float4 v[16];
#pragma unroll
        for (int i = 0; i < 16; ++i) v[i] = row[i];

        // Centered xyz (channels 0..5) while the row loads are in flight.
        const float* gp = xyz + (size_t)(bb * NN + id) * 3;
        const float* cp = new_xyz + (size_t)j * 3;
        const float vx = __fsub_rn(gp[0], cp[0]);
        const float vy = __fsub_rn(gp[1], cp[1]);
        const float vz = __fsub_rn(gp[2], cp[2]);

        const size_t obase = (size_t)bb * NCH * CHS
                           + (size_t)(c0 & (NPOINT - 1)) * KTOT + t;
        out[obase + 0 * (size_t)CHS] = vx;
        out[obase + 1 * (size_t)CHS] = vy;
        out[obase + 2 * (size_t)CHS] = vz;
        out[obase + 3 * (size_t)CHS] = vx;
        out[obase + 4 * (size_t)CHS] = vy;
        out[obase + 5 * (size_t)CHS] = vz;

#pragma unroll
        for (int i = 0; i < 16; ++i) {
            const size_t cb = obase + (size_t)(6 + 4 * i) * CHS;
            out[cb + 0 * (size_t)CHS] = v[i].x;
            out[cb + 1 * (size_t)CHS] = v[i].y;
            out[cb + 2 * (size_t)CHS] = v[i].z;
            out[cb + 3 * (size_t)CHS] = v[i].w;
        }
    }
}

// ---------------------------------------------------------------------------
// Fallbacks (ws too small — not expected; observed ws ~302 MB).
// ---------------------------------------------------------------------------
__global__ __launch_bounds__(256) void ball_query_bf(
    const float* __restrict__ xyz, const float* __restrict__ new_xyz,
    const int* __restrict__ fps_idx, int* __restrict__ idx_out)
{
    const int wave = (blockIdx.x * blockDim.x + threadIdx.x) >> 6;
    const int lane = threadIdx.x & 63;
    if (wave >= BB * NPOINT) return;
    const int b = wave >> 11;
    const float* cp = new_xyz + (size_t)wave * 3;
    const float cx = cp[0], cy = cp[1], cz = cp[2];
    const float r2 = __fmul_rn(0.1f, 0.1f);
    const float* xb = xyz + (size_t)b * NN * 3;
    int* out = idx_out + (size_t)wave * KTOT;
    int count = 0, first = 0;
    for (int base = 0; base < NN; base += 64) {
        const int p = base + lane;
        const float dx = __fsub_rn(cx, xb[p * 3 + 0]);
        const float dy = __fsub_rn(cy, xb[p * 3 + 1]);
        const float dz = __fsub_rn(cz, xb[p * 3 + 2]);
        const float d2 = __fadd_rn(__fadd_rn(__fmul_rn(dx, dx), __fmul_rn(dy, dy)),
                                   __fmul_rn(dz, dz));
        const bool valid = d2 < r2;
        const unsigned long long m = __ballot(valid);
        if (count == 0 && m != 0ull) first = base + __builtin_ctzll(m);
        const int prefix = __builtin_amdgcn_mbcnt_hi(
            (unsigned)(m >> 32), __builtin_amdgcn_mbcnt_lo((unsigned)m, 0u));
        const int slot = count + prefix;
        if (valid && slot < NSAMPLE) out[1 + slot] = p;
        count += (int)__popcll(m);
        if (count >= NSAMPLE) break;
    }
    if (count < NSAMPLE) {
        const int pad = (count > 0) ? first : 0;
        if (lane >= count && lane < NSAMPLE) out[1 + lane] = pad;
    }
    if (lane == 0) out[0] = fps_idx[wave];
}

__global__ __launch_bounds__(256) void gather_kernel(
    const float* __restrict__ xyz, const float* __restrict__ new_xyz,
    const float* __restrict__ features, const int* __restrict__ idx,
    float* __restrict__ out)
{
    const long long total = (long long)BB * NCH * CHS;
    const long long o = (long long)blockIdx.x * blockDim.x + threadIdx.x;
    if (o >= total) return;
    const int s  = (int)(o % KTOT);
    long long t  = o / KTOT;
    const int j  = (int)(t % NPOINT);
    t /= NPOINT;
    const int ch = (int)(t % NCH);
    const int b  = (int)(t / NCH);
    const int id = idx[(long long)(b * NPOINT + j) * KTOT + s];
    float v;
    if (ch < 6) {
        const int c3 = (ch >= 3) ? (ch - 3) : ch;
        v = __fsub_rn(xyz[((long long)b * NN + id) * 3 + c3],
                      new_xyz[((long long)b * NPOINT + j) * 3 + c3]);
    } else {
        v = features[((long long)b * CC + (ch - 6)) * NN + id];
    }
    out[o] = v;
}

extern "C" void kernel_launch(void* const* d_in, const int* in_sizes, int n_in,
                              void* d_out, int out_size, void* d_ws, size_t ws_size,
                              hipStream_t stream) {
    const float* xyz      = (const float*)d_in[0];
    const float* new_xyz  = (const float*)d_in[1];
    const float* features = (const float*)d_in[2];
    const int*   fps_idx  = (const int*)d_in[3];
    float*       out      = (float*)d_out;

    // Workspace layout (16B-aligned offsets). idx slot retained for fallback.
    const size_t off_idx  = 0;
    const size_t sz_idx   = (size_t)BB * CHS * 4;            // 1,081,344
    const size_t off_ft   = off_idx + sz_idx;
    const size_t sz_ft    = (size_t)BB * NN * CC * 4;        // 8,388,608
    const size_t off_spt  = off_ft + sz_ft;
    const size_t sz_spt   = (size_t)BB * NN * 16;            // 524,288
    const size_t off_cs   = off_spt + sz_spt;
    const size_t need_full = off_cs + 2048;                  // ~10.0 MB

    int* idxbuf = (int*)((char*)d_ws + off_idx);

    if (ws_size >= need_full) {
        float*  ft  = (float*) ((char*)d_ws + off_ft);
        float4* spt = (float4*)((char*)d_ws + off_spt);
        int*    cs  = (int*)   ((char*)d_ws + off_cs);

        // Grid build (fused hist+scan+scatter, one block per batch).
        grid_build<<<BB, 1024, 0, stream>>>(xyz, cs, spt);

        // Feature transpose (independent of grid_build).
        feat_transpose<<<BB * (NN / 64), 256, 0, stream>>>(features, ft);

        // Fused ball query + gather: no global idx round-trip.
        bq_gather_fused<<<BB * NPOINT / 4, 256, 0, stream>>>(
            spt, cs, xyz, new_xyz, (const float4*)ft, fps_idx, out);
    } else if (ws_size >= sz_idx) {
        ball_query_bf<<<BB * NPOINT / 4, 256, 0, stream>>>(xyz, new_xyz, fps_idx, idxbuf);
        const long long total = (long long)BB * NCH * CHS;
        gather_kernel<<<(int)((total + 255) / 256), 256, 0, stream>>>(
            xyz, new_xyz, features, idxbuf, out);
    }
}

// Round 2
// 124.911 us; speedup vs baseline: 1.0190x; 1.0190x over previous
//
#include <hip/hip_runtime.h>
#include <stdint.h>
#include <limits.h>

// Problem constants (match reference)
constexpr int BB      = 4;
constexpr int NN      = 8192;
constexpr int NPOINT  = 2048;
constexpr int CC      = 64;
constexpr int NSAMPLE = 32;
constexpr int KTOT    = NSAMPLE + 1;   // fps_idx prepended -> 33
constexpr int NCH     = 3 + 3 + CC;    // 70 output channels
constexpr int CHS     = NPOINT * KTOT; // channel stride in out = 67584

// Spatial grid: 5x5x5 cells of 0.2 over [0,1]^3.
constexpr int   GG     = 5;
constexpr int   NCELL  = GG * GG * GG;        // 125
constexpr float RPADF  = 0.1001f;             // conservative cell-range radius
constexpr int   CAND_CAP = 192;               // in-ball ~Poisson(34); +27 sigma

__device__ __forceinline__ int cell_of(float x, float y, float z) {
    int ix = (int)floorf(x * 5.0f); ix = ix < 0 ? 0 : (ix > 4 ? 4 : ix);
    int iy = (int)floorf(y * 5.0f); iy = iy < 0 ? 0 : (iy > 4 ? 4 : iy);
    int iz = (int)floorf(z * 5.0f); iz = iz < 0 ? 0 : (iz > 4 ? 4 : iz);
    return (ix * GG + iy) * GG + iz;
}

// ---------------------------------------------------------------------------
// Kernel A: fused grid build. One 1024-thread block per batch: LDS histogram,
// wave-0 scan, LDS-cursor scatter into cell-sorted AoS float4
// (x,y,z,bitcast(origidx)). Points cached in registers between phases.
// ---------------------------------------------------------------------------
__global__ __launch_bounds__(1024) void grid_build(
    const float* __restrict__ xyz, int* __restrict__ cellstartg,
    float4* __restrict__ spt)
{
    __shared__ int hist[NCELL];
    __shared__ int csl[NCELL + 1];
    __shared__ int cur[NCELL];
    const int b = blockIdx.x;
    const int t = threadIdx.x;
    if (t < NCELL) hist[t] = 0;
    __syncthreads();
    const float* xb = xyz + (size_t)b * NN * 3;
    float px[NN / 1024], py[NN / 1024], pz[NN / 1024];
    int   pc[NN / 1024];
#pragma unroll
    for (int k = 0; k < NN / 1024; ++k) {
        const float* p = xb + (size_t)(t + k * 1024) * 3;
        px[k] = p[0]; py[k] = p[1]; pz[k] = p[2];
        pc[k] = cell_of(px[k], py[k], pz[k]);
        atomicAdd(&hist[pc[k]], 1);
    }
    __syncthreads();
    if (t < 64) {                         // wave 0: scan 125 counts
        int x0 = hist[t];
        int x1 = (t + 64 < NCELL) ? hist[t + 64] : 0;
#pragma unroll
        for (int d = 1; d < 64; d <<= 1) {
            int t0 = __shfl_up(x0, d);
            int t1 = __shfl_up(x1, d);
            if (t >= d) { x0 += t0; x1 += t1; }
        }
        x1 += __shfl(x0, 63);
        if (t == 0) csl[0] = 0;
        csl[1 + t] = x0;
        if (t <= 60) csl[65 + t] = x1;
    }
    __syncthreads();
    if (t < NCELL + 1) cellstartg[b * (NCELL + 1) + t] = csl[t];
    if (t < NCELL)     cur[t] = csl[t];
    __syncthreads();
#pragma unroll
    for (int k = 0; k < NN / 1024; ++k) {
        const int pos = atomicAdd(&cur[pc[k]], 1);
        spt[b * NN + pos] = make_float4(px[k], py[k], pz[k],
                                        __int_as_float(t + k * 1024));
    }
}

// ---------------------------------------------------------------------------
// Kernel B: grid ball query. One wave per centroid; exact d2 < r2 via the
// numpy-fp32 __f*_rn chain; rank-select emits first-32-in-index-order;
// pad = min hit; slot 0 = fps_idx.
// ---------------------------------------------------------------------------
__global__ __launch_bounds__(256) void ball_query_grid(
    const float4* __restrict__ spt, const int* __restrict__ cellstart,
    const float* __restrict__ new_xyz, const int* __restrict__ fps_idx,
    int*         __restrict__ idx_out)
{
    __shared__ int cand[4][CAND_CAP];
    const int w    = threadIdx.x >> 6;
    const int lane = threadIdx.x & 63;
    const int wave = blockIdx.x * 4 + w;     // centroid id, 0..8191
    const int b    = wave >> 11;             // / NPOINT

    const float* cp = new_xyz + (size_t)wave * 3;
    const float cx = cp[0], cy = cp[1], cz = cp[2];
    const float r2 = __fmul_rn(0.1f, 0.1f);

    int ix0 = (int)floorf((cx - RPADF) * 5.0f); ix0 = ix0 < 0 ? 0 : ix0;
    int ix1 = (int)floorf((cx + RPADF) * 5.0f); ix1 = ix1 > 4 ? 4 : ix1;
    int iy0 = (int)floorf((cy - RPADF) * 5.0f); iy0 = iy0 < 0 ? 0 : iy0;
    int iy1 = (int)floorf((cy + RPADF) * 5.0f); iy1 = iy1 > 4 ? 4 : iy1;
    int iz0 = (int)floorf((cz - RPADF) * 5.0f); iz0 = iz0 < 0 ? 0 : iz0;
    int iz1 = (int)floorf((cz + RPADF) * 5.0f); iz1 = iz1 > 4 ? 4 : iz1;

    const int* cs = cellstart + b * (NCELL + 1);
    const int gb  = b * NN;
    int cnt = 0;

    for (int ix = ix0; ix <= ix1; ++ix) {
        for (int iy = iy0; iy <= iy1; ++iy) {
            const int cbase = (ix * GG + iy) * GG;
            const int st = cs[cbase + iz0];
            const int en = cs[cbase + iz1 + 1];
            for (int base = st; base < en; base += 64) {
                const int pos = base + lane;
                const bool inb = pos < en;
                const float4 q = spt[gb + (inb ? pos : st)];
                const int oid = __float_as_int(q.w);
                const float dx = __fsub_rn(cx, q.x);
                const float dy = __fsub_rn(cy, q.y);
                const float dz = __fsub_rn(cz, q.z);
                const float d2 = __fadd_rn(__fadd_rn(__fmul_rn(dx, dx), __fmul_rn(dy, dy)),
                                           __fmul_rn(dz, dz));
                const bool valid = inb && (d2 < r2);
                const unsigned long long m = __ballot(valid);
                if (m != 0ull) {
                    const int prefix = __builtin_amdgcn_mbcnt_hi(
                        (unsigned)(m >> 32), __builtin_amdgcn_mbcnt_lo((unsigned)m, 0u));
                    const int slot = cnt + prefix;
                    if (valid && slot < CAND_CAP) cand[w][slot] = oid;
                    cnt += (int)__popcll(m);
                }
            }
        }
    }

    const int K = cnt > CAND_CAP ? CAND_CAP : cnt;

    int v0 = (lane       < K) ? cand[w][lane]       : INT_MAX;
    int v1 = (lane + 64  < K) ? cand[w][lane + 64]  : INT_MAX;
    int v2 = (lane + 128 < K) ? cand[w][lane + 128] : INT_MAX;
    int rk0 = 0, rk1 = 0, rk2 = 0;
    for (int j = 0; j < K; ++j) {
        const int sv = cand[w][j];
        rk0 += (sv < v0); rk1 += (sv < v1); rk2 += (sv < v2);
    }
    int* out = idx_out + (size_t)wave * KTOT;
    if (lane       < K && rk0 < NSAMPLE) out[1 + rk0] = v0;
    if (lane + 64  < K && rk1 < NSAMPLE) out[1 + rk1] = v1;
    if (lane + 128 < K && rk2 < NSAMPLE) out[1 + rk2] = v2;

    if (K < NSAMPLE) {
        int mn = v0;
#pragma unroll
        for (int off = 32; off >= 1; off >>= 1) {
            const int o = __shfl_xor(mn, off);
            mn = o < mn ? o : mn;
        }
        const int pad = (K > 0) ? mn : 0;
        if (lane >= K && lane < NSAMPLE) out[1 + lane] = pad;
    }
    if (lane == 0) out[0] = fps_idx[wave];
}

// ---------------------------------------------------------------------------
// Kernel C: features (B,C,N) -> ft (B,N,C), LDS-tiled 64x64.
// ---------------------------------------------------------------------------
__global__ __launch_bounds__(256) void feat_transpose(
    const float* __restrict__ f, float* __restrict__ ft)
{
    __shared__ float tile[64 * 65];
    const int blk = blockIdx.x;          // B * (N/64) = 512
    const int b   = blk >> 7;
    const int n0  = (blk & 127) << 6;
    const int w   = threadIdx.x >> 6, l = threadIdx.x & 63;
#pragma unroll
    for (int i = 0; i < 16; ++i) {
        const int c = i * 4 + w;
        tile[l * 65 + c] = f[((size_t)b * CC + c) * NN + n0 + l];  // coalesced read
    }
    __syncthreads();
#pragma unroll
    for (int i = 0; i < 16; ++i) {
        const int flat = i * 256 + threadIdx.x;                    // n*64 + c
        ft[((size_t)b * NN + n0) * CC + flat] = tile[(flat >> 6) * 65 + (flat & 63)];
    }
}

// ---------------------------------------------------------------------------
// Kernel D: gather v7 — LDS-decoupled. Block = 256 threads per 64 slots.
// Phase A: centered xyz -> tile ch 0..5. Phase B: feature rows loaded with
// 4 independent float4 insts per thread (NO interleaved global stores ->
// full MLP), written channel-major to LDS (stride 66 -> <=2-way banks = free).
// Phase C: pure store stream — per wave-inst one channel plane x 64
// consecutive floats, zero load dependencies.
// v3/v4 failed because each thread serialized load->store->load (~16 memory
// round-trips, VGPR_Count=8 rolling buffer); the barrier splits that chain.
// Round-1 fusion experiment (bq+gather in one kernel) regressed 3.5 us:
// phase-2 ran on 132/256 lanes and lost this decoupled store stream. Reverted.
// ---------------------------------------------------------------------------
constexpr int TPAD = 66;   // tile stride: bank = (2*ch + col) % 32 -> 2-way max
__global__ __launch_bounds__(256) void gather_v7(
    const float* __restrict__ xyz, const float* __restrict__ new_xyz,
    const float4* __restrict__ ft4, const int* __restrict__ idx,
    float* __restrict__ out)
{
    __shared__ float tile[NCH][TPAD];    // 70 x 66 x 4B = 18.5 KB
    const int blk = blockIdx.x;          // 4224 blocks
    const int t   = threadIdx.x;
    const int jj0 = blk * 64;            // global slot base; CHS % 64 == 0
    const int b   = jj0 / CHS;
    const int jjb = jj0 - b * CHS;       // slot base within batch

    // Phase A: slot ids + centered xyz channels 0..5 (threads 0..63).
    if (t < 64) {
        const int id = idx[jj0 + t];
        const int j  = (jjb + t) / KTOT;
        const float* gp = xyz + (size_t)(b * NN + id) * 3;
        const float* cp = new_xyz + (size_t)(b * NPOINT + j) * 3;
        const float vx = __fsub_rn(gp[0], cp[0]);
        const float vy = __fsub_rn(gp[1], cp[1]);
        const float vz = __fsub_rn(gp[2], cp[2]);
        tile[0][t] = vx; tile[1][t] = vy; tile[2][t] = vz;
        tile[3][t] = vx; tile[4][t] = vy; tile[5][t] = vz;
    }

    // Phase B: feature rows -> LDS, channel-major. Thread group of 4 lanes
    // (g=0..3) covers row r's 16 float4s; load inst i reads row[4i+g] so each
    // group requests one contiguous 64B line; all 4 loads independent.
    {
        const int r = t >> 2, g = t & 3;
        const int id = idx[jj0 + r];                    // 4 lanes same addr (L1)
        const float4* row = ft4 + ((size_t)b * NN + id) * (CC / 4);
        float4 v[4];
#pragma unroll
        for (int i = 0; i < 4; ++i) v[i] = row[4 * i + g];
#pragma unroll
        for (int i = 0; i < 4; ++i) {
            const int c0 = 6 + 16 * i + 4 * g;          // channels of row[4i+g]
            tile[c0 + 0][r] = v[i].x;
            tile[c0 + 1][r] = v[i].y;
            tile[c0 + 2][r] = v[i].z;
            tile[c0 + 3][r] = v[i].w;
        }
    }
    __syncthreads();

    // Phase C: stream 70 planes x 64 consecutive positions. Wave w handles
    // plane 4k+w -> per wave-inst: one plane, 256B coalesced store.
    const int w   = t >> 6;
    const int col = t & 63;
    const size_t ob = (size_t)b * NCH * CHS + (size_t)jjb + col;
#pragma unroll
    for (int k = 0; k < 18; ++k) {
        const int ch = 4 * k + w;
        if (ch < NCH) out[ob + (size_t)ch * CHS] = tile[ch][col];
    }
}

// ---------------------------------------------------------------------------
// Fallbacks (ws too small — not expected; observed ws ~302 MB).
// ---------------------------------------------------------------------------
__global__ __launch_bounds__(256) void ball_query_bf(
    const float* __restrict__ xyz, const float* __restrict__ new_xyz,
    const int* __restrict__ fps_idx, int* __restrict__ idx_out)
{
    const int wave = (blockIdx.x * blockDim.x + threadIdx.x) >> 6;
    const int lane = threadIdx.x & 63;
    if (wave >= BB * NPOINT) return;
    const int b = wave >> 11;
    const float* cp = new_xyz + (size_t)wave * 3;
    const float cx = cp[0], cy = cp[1], cz = cp[2];
    const float r2 = __fmul_rn(0.1f, 0.1f);
    const float* xb = xyz + (size_t)b * NN * 3;
    int* out = idx_out + (size_t)wave * KTOT;
    int count = 0, first = 0;
    for (int base = 0; base < NN; base += 64) {
        const int p = base + lane;
        const float dx = __fsub_rn(cx, xb[p * 3 + 0]);
        const float dy = __fsub_rn(cy, xb[p * 3 + 1]);
        const float dz = __fsub_rn(cz, xb[p * 3 + 2]);
        const float d2 = __fadd_rn(__fadd_rn(__fmul_rn(dx, dx), __fmul_rn(dy, dy)),
                                   __fmul_rn(dz, dz));
        const bool valid = d2 < r2;
        const unsigned long long m = __ballot(valid);
        if (count == 0 && m != 0ull) first = base + __builtin_ctzll(m);
        const int prefix = __builtin_amdgcn_mbcnt_hi(
            (unsigned)(m >> 32), __builtin_amdgcn_mbcnt_lo((unsigned)m, 0u));
        const int slot = count + prefix;
        if (valid && slot < NSAMPLE) out[1 + slot] = p;
        count += (int)__popcll(m);
        if (count >= NSAMPLE) break;
    }
    if (count < NSAMPLE) {
        const int pad = (count > 0) ? first : 0;
        if (lane >= count && lane < NSAMPLE) out[1 + lane] = pad;
    }
    if (lane == 0) out[0] = fps_idx[wave];
}

__global__ __launch_bounds__(256) void gather_kernel(
    const float* __restrict__ xyz, const float* __restrict__ new_xyz,
    const float* __restrict__ features, const int* __restrict__ idx,
    float* __restrict__ out)
{
    const long long total = (long long)BB * NCH * CHS;
    const long long o = (long long)blockIdx.x * blockDim.x + threadIdx.x;
    if (o >= total) return;
    const int s  = (int)(o % KTOT);
    long long t  = o / KTOT;
    const int j  = (int)(t % NPOINT);
    t /= NPOINT;
    const int ch = (int)(t % NCH);
    const int b  = (int)(t / NCH);
    const int id = idx[(long long)(b * NPOINT + j) * KTOT + s];
    float v;
    if (ch < 6) {
        const int c3 = (ch >= 3) ? (ch - 3) : ch;
        v = __fsub_rn(xyz[((long long)b * NN + id) * 3 + c3],
                      new_xyz[((long long)b * NPOINT + j) * 3 + c3]);
    } else {
        v = features[((long long)b * CC + (ch - 6)) * NN + id];
    }
    out[o] = v;
}

extern "C" void kernel_launch(void* const* d_in, const int* in_sizes, int n_in,
                              void* d_out, int out_size, void* d_ws, size_t ws_size,
                              hipStream_t stream) {
    const float* xyz      = (const float*)d_in[0];
    const float* new_xyz  = (const float*)d_in[1];
    const float* features = (const float*)d_in[2];
    const int*   fps_idx  = (const int*)d_in[3];
    float*       out      = (float*)d_out;

    // Workspace layout (16B-aligned offsets).
    const size_t off_idx  = 0;
    const size_t sz_idx   = (size_t)BB * CHS * 4;            // 1,081,344
    const size_t off_ft   = off_idx + sz_idx;
    const size_t sz_ft    = (size_t)BB * NN * CC * 4;        // 8,388,608
    const size_t off_spt  = off_ft + sz_ft;
    const size_t sz_spt   = (size_t)BB * NN * 16;            // 524,288
    const size_t off_cs   = off_spt + sz_spt;
    const size_t need_full = off_cs + 2048;                  // ~10.0 MB

    int* idxbuf = (int*)((char*)d_ws + off_idx);

    if (ws_size >= need_full) {
        float*  ft  = (float*) ((char*)d_ws + off_ft);
        float4* spt = (float4*)((char*)d_ws + off_spt);
        int*    cs  = (int*)   ((char*)d_ws + off_cs);

        // Grid build (fused hist+scan+scatter, one block per batch).
        grid_build<<<BB, 1024, 0, stream>>>(xyz, cs, spt);

        // Ball query over grid cells. One wave per centroid, 4 waves/block.
        ball_query_grid<<<BB * NPOINT / 4, 256, 0, stream>>>(
            spt, cs, new_xyz, fps_idx, idxbuf);

        // Gather: transpose features, then LDS-decoupled gather.
        feat_transpose<<<BB * (NN / 64), 256, 0, stream>>>(features, ft);
        gather_v7<<<BB * CHS / 64, 256, 0, stream>>>(xyz, new_xyz, (const float4*)ft,
                                                     idxbuf, out);
    } else if (ws_size >= sz_idx) {
        ball_query_bf<<<BB * NPOINT / 4, 256, 0, stream>>>(xyz, new_xyz, fps_idx, idxbuf);
        const long long total = (long long)BB * NCH * CHS;
        gather_kernel<<<(int)((total + 255) / 256), 256, 0, stream>>>(
            xyz, new_xyz, features, idxbuf, out);
    }
}